// Round 6
// baseline (485.467 us; speedup 1.0000x reference)
//
#include <hip/hip_runtime.h>
#include <math.h>

#define B 128
#define D 128
#define NMEM 100000
#define KTOT 8194
#define NEGK 8192
#define CHUNKX 33              // ceil(8194/256)
#define COPY_BLOCKS 512
#define GATHER_BLOCKS (CHUNKX * B)

// ws layout (floats): acc[128][12] @ 0 ; sps[128][6] @ 1536 ; total 2304 floats
#define WS_ACC 0
#define WS_SPS 1536
#define WS_FLOATS 2304

typedef float floatx4 __attribute__((ext_vector_type(4)));  // true vector type for nontemporal builtins

__global__ void zero_ws(float* __restrict__ ws) {
    const int t = threadIdx.x;  // 256 threads, 9 floats each covers 2304
    #pragma unroll
    for (int j = 0; j < 9; ++j) {
        const int i = t * 9 + j;
        if (i < WS_FLOATS) ws[i] = 0.f;
    }
}

__device__ __forceinline__ void dot4(float4& a, const float4 m, const float4 e) {
    a.x = fmaf(m.x, e.x, a.x);
    a.y = fmaf(m.y, e.y, a.y);
    a.z = fmaf(m.z, e.z, a.z);
    a.w = fmaf(m.w, e.w, a.w);
}

// Grid = COPY_BLOCKS + GATHER_BLOCKS, 256 threads.
// Blocks [0, COPY_BLOCKS): stream mems -> out (overlaps with gather stalls).
// Blocks [COPY_BLOCKS, ...): one k per THREAD — no cross-lane reduction per k.
__global__ __launch_bounds__(256) void fused_main(
        const float* __restrict__ emb0, const float* __restrict__ emb1,
        const float* __restrict__ mem0, const float* __restrict__ mem1,
        const int* __restrict__ pos_idx, const int* __restrict__ neg_idx,
        float* __restrict__ ws, float* __restrict__ o0, float* __restrict__ o1) {
    const int bid = blockIdx.x;
    const int tid = threadIdx.x;
    const float INV_TAU = 1.0f / 0.07f;
    const float INV3 = 1.0f / 3.0f;

    if (bid < COPY_BLOCKS) {
        const int n4 = NMEM * D / 4;  // 3,200,000
        const floatx4* m04 = (const floatx4*)mem0;
        const floatx4* m14 = (const floatx4*)mem1;
        floatx4* o04 = (floatx4*)o0;
        floatx4* o14 = (floatx4*)o1;
        for (int i = bid * 256 + tid; i < n4; i += COPY_BLOCKS * 256) {
            const floatx4 v0 = __builtin_nontemporal_load(m04 + i);
            const floatx4 v1 = __builtin_nontemporal_load(m14 + i);
            __builtin_nontemporal_store(v0, o04 + i);
            __builtin_nontemporal_store(v1, o14 + i);
        }
        return;
    }

    const int g = bid - COPY_BLOCKS;
    const int c = g % CHUNKX;
    const int b = g / CHUNKX;
    const int k = c * 256 + tid;

    float st[12];
    #pragma unroll
    for (int j = 0; j < 12; ++j) st[j] = 0.f;

    if (k < KTOT) {
        const int r = (k < 2) ? pos_idx[b * 2 + k] : neg_idx[b * NEGK + (k - 2)];
        const float4* m0p = (const float4*)(mem0 + (size_t)r * D);
        const float4* m1p = (const float4*)(mem1 + (size_t)r * D);
        const float4* e0p = (const float4*)(emb0 + b * D);  // b uniform -> s_load
        const float4* e1p = (const float4*)(emb1 + b * D);
        float4 aij = {0,0,0,0}, aii = {0,0,0,0}, aji = {0,0,0,0}, ajj = {0,0,0,0};
        #pragma unroll 8
        for (int d4 = 0; d4 < 32; ++d4) {
            const float4 m0 = m0p[d4];
            const float4 m1 = m1p[d4];
            const float4 e0 = e0p[d4];
            const float4 e1 = e1p[d4];
            dot4(aij, m0, e1);  // cij    = mem0 . emb1
            dot4(aii, m0, e0);  // intra0 = mem0 . emb0
            dot4(aji, m1, e0);  // cji    = mem1 . emb0
            dot4(ajj, m1, e1);  // intra1 = mem1 . emb1
        }
        const float cij = (aij.x + aij.y + aij.z + aij.w) * INV_TAU;
        const float ci0 = (aii.x + aii.y + aii.z + aii.w) * INV_TAU;
        const float cji = (aji.x + aji.y + aji.z + aji.w) * INV_TAU;
        const float ci1 = (ajj.x + ajj.y + ajj.z + ajj.w) * INV_TAU;
        const float e3ij = __expf(cij * INV3), e3ji = __expf(cji * INV3);
        st[0] = __expf(cij);
        st[1] = __expf(cji);
        st[4] = e3ij;
        st[5] = e3ji;
        st[8] = e3ji * (cji - cij);
        st[9] = e3ij * (cij - cji);
        if (k >= 1) {  // intra logits cover k in [1, KTOT)
            const float e3i0 = __expf(ci0 * INV3), e3i1 = __expf(ci1 * INV3);
            st[2] = __expf(ci0);
            st[3] = __expf(ci1);
            st[6] = e3i0;
            st[7] = e3i1;
            st[10] = e3i1 * (ci1 - ci0);
            st[11] = e3i0 * (ci0 - ci1);
        }
        if (k == 0) { ws[WS_SPS + b * 6 + 0] = cij; ws[WS_SPS + b * 6 + 2] = cji; }
        if (k == 1) { ws[WS_SPS + b * 6 + 1] = cij; ws[WS_SPS + b * 6 + 3] = cji;
                      ws[WS_SPS + b * 6 + 4] = ci0; ws[WS_SPS + b * 6 + 5] = ci1; }
    }

    // block reduction: wave shuffle then LDS, then 12 atomics per block
    #pragma unroll
    for (int j = 0; j < 12; ++j) {
        #pragma unroll
        for (int off = 1; off < 64; off <<= 1) st[j] += __shfl_xor(st[j], off, 64);
    }
    __shared__ float red[4][12];
    const int w = tid >> 6, lane = tid & 63;
    if (lane == 0) {
        #pragma unroll
        for (int j = 0; j < 12; ++j) red[w][j] = st[j];
    }
    __syncthreads();
    if (tid < 12)
        atomicAdd(&ws[WS_ACC + b * 12 + tid],
                  red[0][tid] + red[1][tid] + red[2][tid] + red[3][tid]);
}

// Grid = 128 blocks x 128 threads. Every block: momentum update for b=blockIdx.x
// (last-write-wins on dup p0). Block 0 additionally computes the 4 scalars.
__global__ void finalize_update(const float* __restrict__ ws, float* __restrict__ out,
                                const float* __restrict__ emb0, const float* __restrict__ emb1,
                                const float* __restrict__ mem0, const float* __restrict__ mem1,
                                const int* __restrict__ pos_idx,
                                float* __restrict__ o0, float* __restrict__ o1) {
    const int blk = blockIdx.x;
    const int tid = threadIdx.x;  // 128
    {
        const int lane = tid & 63;
        const int net = tid >> 6;
        const int p0 = pos_idx[blk * 2];
        bool skip = false;
        for (int b2 = blk + 1; b2 < B; ++b2)
            if (pos_idx[b2 * 2] == p0) skip = true;  // numpy scatter: last write wins
        if (!skip) {
            const float* mem = net ? mem1 : mem0;
            const float* emb = net ? emb1 : emb0;
            float* o = net ? o1 : o0;
            const float2 mv = *(const float2*)(mem + (size_t)p0 * D + 2 * lane);
            const float2 ev = *(const float2*)(emb + blk * D + 2 * lane);
            const float ux = 0.5f * mv.x + 0.5f * ev.x;
            const float uy = 0.5f * mv.y + 0.5f * ev.y;
            float ss = ux * ux + uy * uy;
            #pragma unroll
            for (int off = 1; off < 64; off <<= 1) ss += __shfl_xor(ss, off, 64);
            const float inv = 1.0f / sqrtf(ss);
            float2 wv; wv.x = ux * inv; wv.y = uy * inv;
            *(float2*)(o + (size_t)p0 * D + 2 * lane) = wv;
        }
    }
    if (blk != 0) return;

    const int b = tid;
    float a[12];
    #pragma unroll
    for (int j = 0; j < 12; ++j) a[j] = ws[WS_ACC + b * 12 + j];
    const float* e = ws + WS_SPS + b * 6;
    const float cij0 = e[0], cij1 = e[1], cji0 = e[2], cji1 = e[3], i01 = e[4], i11 = e[5];
    // a: 0 s1ij, 1 s1ji, 2 s1i0, 3 s1i1, 4 s3ij, 5 s3ji, 6 s3i0, 7 s3i1, 8 wa, 9 wb, 10 wc, 11 wd
    const float icl_b = -((cij0 + cij1) * 0.5f - __logf(a[0]))
                        - ((cji0 + cji1) * 0.5f - __logf(a[1]));
    const float vcl_b = -(i01 - __logf(a[2])) - (i11 - __logf(a[3]));
    // kld(X,Y)+kld(Y,X): lse terms cancel; = 3/B * (wa/s3_Y + wb/s3_X), B-mean below
    const float sicl_b = 3.0f * (a[8] / a[5] + a[9] / a[4]);
    const float svcl_b = 3.0f * (a[10] / a[7] + a[11] / a[6]);
    __shared__ float r[4][128];
    r[0][b] = vcl_b; r[1][b] = svcl_b; r[2][b] = icl_b; r[3][b] = sicl_b;
    __syncthreads();
    for (int s = 64; s > 0; s >>= 1) {
        if (b < s) {
            r[0][b] += r[0][b + s]; r[1][b] += r[1][b + s];
            r[2][b] += r[2][b + s]; r[3][b] += r[3][b + s];
        }
        __syncthreads();
    }
    if (b == 0) {
        out[0] = r[0][0] * (1.0f / 128.f);
        out[1] = r[1][0] * (1.0f / 128.f);
        out[2] = r[2][0] * (1.0f / 128.f);
        out[3] = r[3][0] * (1.0f / 128.f);
    }
}

extern "C" void kernel_launch(void* const* d_in, const int* in_sizes, int n_in,
                              void* d_out, int out_size, void* d_ws, size_t ws_size,
                              hipStream_t stream) {
    const float* emb0 = (const float*)d_in[0];
    const float* emb1 = (const float*)d_in[1];
    const float* mem0 = (const float*)d_in[2];
    const float* mem1 = (const float*)d_in[3];
    const int* pos_idx = (const int*)d_in[4];
    const int* neg_idx = (const int*)d_in[5];
    float* out = (float*)d_out;
    float* ws = (float*)d_ws;  // 2304 floats = 9.2 KB

    float* out_m0 = out + 4;
    float* out_m1 = out + 4 + NMEM * D;

    zero_ws<<<1, 256, 0, stream>>>(ws);
    fused_main<<<COPY_BLOCKS + GATHER_BLOCKS, 256, 0, stream>>>(
        emb0, emb1, mem0, mem1, pos_idx, neg_idx, ws, out_m0, out_m1);
    finalize_update<<<128, 128, 0, stream>>>(ws, out, emb0, emb1, mem0, mem1,
                                             pos_idx, out_m0, out_m1);
}